// Round 2
// baseline (67.562 us; speedup 1.0000x reference)
//
#include <hip/hip_runtime.h>
#include <hip/hip_bf16.h>

// ---------------------------------------------------------------------------
// PointNet2 FP module, fused: knn(k=3)+interp -> H-tile in LDS -> GEMM1(+b,relu)
// -> h1-tile in LDS -> GEMM2(+b,relu) -> out.  One block = 64 skip rows.
// B=16, N_in=4096, N_skip=16384, C_in=256, C_skip=128, d_cat=387 (pad 416)
// ---------------------------------------------------------------------------

typedef __bf16 bf16x8 __attribute__((ext_vector_type(8)));
typedef float  f32x4  __attribute__((ext_vector_type(4)));

__device__ __forceinline__ unsigned short f2bf(float f) {
  __hip_bfloat16 h = __float2bfloat16(f);
  return __builtin_bit_cast(unsigned short, h);
}

#define GLDS16(G, L)                                                          \
  __builtin_amdgcn_global_load_lds(                                           \
      (const __attribute__((address_space(1))) void*)(G),                     \
      (__attribute__((address_space(3))) void*)(L), 16, 0, 0)

#define BAR()    __builtin_amdgcn_s_barrier()
#define WAITV(N) asm volatile("s_waitcnt vmcnt(" #N ")" ::: "memory")
#define WAITL()  asm volatile("s_waitcnt lgkmcnt(0)" ::: "memory")

static constexpr int MROWS = 16384;
static constexpr int KPAD  = 416;   // 13 * 32
static constexpr int KREAL = 387;
static constexpr int NK1   = 13;
static constexpr int NK2   = 8;
static constexpr int HSTR  = 424;   // H-tile row stride (shorts), pad for banks
static constexpr int H1STR = 264;   // h1-tile row stride (shorts)

// ---------------- prep: W1t[256][416], W2t[256][256] bf16 (LDS transpose) ---
__global__ __launch_bounds__(256) void prep_w(
    const float* __restrict__ W1, const float* __restrict__ W2,
    unsigned short* __restrict__ W1t, unsigned short* __restrict__ W2t)
{
  __shared__ float T[64][65];
  int b = blockIdx.x;
  const float* S; unsigned short* D; int KP, Kreal, kb, nb;
  if (b < 28) { S = W1; D = W1t; KP = KPAD; Kreal = KREAL; kb = b >> 2; nb = b & 3; }
  else { b -= 28; S = W2; D = W2t; KP = 256; Kreal = 256; kb = b >> 2; nb = b & 3; }
  const int k0 = kb << 6, n0 = nb << 6;
  const int tr = threadIdx.x >> 4, tc = threadIdx.x & 15;
#pragma unroll
  for (int i = 0; i < 4; ++i) {
    const int k = k0 + i * 16 + tr;
    float4 v = make_float4(0.f, 0.f, 0.f, 0.f);
    if (k < Kreal) v = *(const float4*)(S + (size_t)k * 256 + n0 + tc * 4);
    T[i * 16 + tr][tc * 4 + 0] = v.x;
    T[i * 16 + tr][tc * 4 + 1] = v.y;
    T[i * 16 + tr][tc * 4 + 2] = v.z;
    T[i * 16 + tr][tc * 4 + 3] = v.w;
  }
  __syncthreads();
#pragma unroll
  for (int i = 0; i < 4; ++i) {
    const int n = n0 + i * 16 + tr;
    const int k = k0 + tc * 4;
    if (k < KP) {
      ushort4 o;
      o.x = f2bf(T[tc * 4 + 0][i * 16 + tr]);
      o.y = f2bf(T[tc * 4 + 1][i * 16 + tr]);
      o.z = f2bf(T[tc * 4 + 2][i * 16 + tr]);
      o.w = f2bf(T[tc * 4 + 3][i * 16 + tr]);
      *(ushort4*)(D + (size_t)n * KP + k) = o;
    }
  }
}

// B-tile stage: [256 rows][32 k] bf16 into buf, chunk-XOR pre-swizzled source.
// 4 GLDS16 per thread (=> vmcnt 4 per tile). LDS dest linear; read side XORs.
__device__ __forceinline__ void stage_tile(const unsigned short* __restrict__ W,
                                           int Krow, int ks,
                                           unsigned short* buf, int tid, int wid)
{
#pragma unroll
  for (int ro = 0; ro < 4; ++ro) {
    const int r  = ro * 64 + (tid >> 2);
    const int c  = tid & 3;
    const int cs = c ^ ((r >> 1) & 3);
    const unsigned short* src = W + (size_t)r * Krow + ks * 32 + cs * 8;
    unsigned short* dst = buf + ro * 2048 + wid * 512;  // wave-uniform base
    GLDS16(src, dst);
  }
}

// ---------------------------- the fused kernel ------------------------------
__global__ __launch_bounds__(256) void fp_fused(
    const float* __restrict__ in_x,      // [4096, 256]
    const float* __restrict__ in_pos,    // [4096, 3]
    const float* __restrict__ skip_x,    // [16384, 128]
    const float* __restrict__ skip_pos,  // [16384, 3]
    const unsigned short* __restrict__ W1t,  // [256][416] bf16
    const unsigned short* __restrict__ W2t,  // [256][256] bf16
    const float* __restrict__ bias1, const float* __restrict__ bias2,
    float* __restrict__ out)             // [16384, 256]
{
  __shared__ unsigned short Hs[64 * HSTR];   // 54,272 B ; h1 aliases this
  __shared__ unsigned short Bst[2 * 8192];   // 32,768 B (2 x [256][32])
  __shared__ float Ps[768];                  //  3,072 B (SoA in_pos of batch)

  const int tid  = threadIdx.x, lane = tid & 63, wid = tid >> 6;
  const int m0   = blockIdx.x << 6;          // first skip row of block
  const int ib   = (m0 >> 10) << 8;          // first in-point of batch
  const int fr   = lane & 15, g = lane >> 4;
  const int wc   = wid << 6;                 // wave's 64-col band

  // bias preload (consumed only in epilogues; retires long before)
  f32x4 b1v[4], b2v[4];
#pragma unroll
  for (int mc = 0; mc < 4; ++mc) {
    b1v[mc] = *(const f32x4*)(bias1 + wc + mc * 16 + g * 4);
    b2v[mc] = *(const f32x4*)(bias2 + wc + mc * 16 + g * 4);
  }

  // stage batch in_pos SoA
  {
    const float* bp = in_pos + (size_t)ib * 3;
#pragma unroll
    for (int i = tid; i < 768; i += 256) Ps[(i % 3) * 256 + i / 3] = bp[i];
  }
  WAITL(); BAR();

  // GEMM1 prologue staging — latency hides under the whole KNN phase
  stage_tile(W1t, KPAD, 0, Bst, tid, wid);
  stage_tile(W1t, KPAD, 1, Bst + 8192, tid, wid);

  // hoist candidate coords to registers (reused for all 16 points)
  float Pxr[4], Pyr[4], Pzr[4];
#pragma unroll
  for (int q = 0; q < 4; ++q) {
    Pxr[q] = Ps[lane + q * 64];
    Pyr[q] = Ps[256 + lane + q * 64];
    Pzr[q] = Ps[512 + lane + q * 64];
  }
  float spv = 0.f;
  if (lane < 48) spv = skip_pos[(size_t)(m0 + wid * 16) * 3 + lane];

  // ---- KNN(k=3) + interpolate + concat -> H-tile rows in LDS ----
  for (int p = 0; p < 16; ++p) {
    const int lr = wid * 16 + p;
    const int s  = m0 + lr;
    const float sx = __shfl(spv, 3 * p + 0);
    const float sy = __shfl(spv, 3 * p + 1);
    const float sz = __shfl(spv, 3 * p + 2);

    float d2[4];
#pragma unroll
    for (int q = 0; q < 4; ++q) {   // numpy op-order, no fma contraction
      const float dx = __fsub_rn(sx, Pxr[q]);
      const float dy = __fsub_rn(sy, Pyr[q]);
      const float dz = __fsub_rn(sz, Pzr[q]);
      d2[q] = __fadd_rn(__fadd_rn(__fmul_rn(dx, dx), __fmul_rn(dy, dy)),
                        __fmul_rn(dz, dz));
    }
    int gsel[3]; float wsel[3]; float wsum = 0.f;
#pragma unroll
    for (int t = 0; t < 3; ++t) {
      float bd = d2[0]; int bi = lane;
#pragma unroll
      for (int q = 1; q < 4; ++q) {
        const int i = lane + (q << 6);
        if (d2[q] < bd) { bd = d2[q]; bi = i; }
      }
#pragma unroll
      for (int mk = 1; mk < 64; mk <<= 1) {   // argmin butterfly, low-idx tiebreak
        const float od = __shfl_xor(bd, mk);
        const int   oi = __shfl_xor(bi, mk);
        if (od < bd || (od == bd && oi < bi)) { bd = od; bi = oi; }
      }
      const bool win = ((bi & 63) == lane);
      const int  qw  = bi >> 6;               // static-index removal (no scratch)
      d2[0] = (win && qw == 0) ? 3.4e38f : d2[0];
      d2[1] = (win && qw == 1) ? 3.4e38f : d2[1];
      d2[2] = (win && qw == 2) ? 3.4e38f : d2[2];
      d2[3] = (win && qw == 3) ? 3.4e38f : d2[3];
      gsel[t] = bi;
      // dist == sqrt(selected d2) bitwise (squares kill the sign flip)
      const float w = 1.0f / fmaxf(sqrtf(bd), 1e-10f);
      wsel[t] = w; wsum += w;
    }
    const float denom = wsum + 1e-16f;
    const float w0 = wsel[0] / denom, w1 = wsel[1] / denom, w2 = wsel[2] / denom;

    const f32x4 a = *(const f32x4*)(in_x + (size_t)(ib + gsel[0]) * 256 + lane * 4);
    const f32x4 b = *(const f32x4*)(in_x + (size_t)(ib + gsel[1]) * 256 + lane * 4);
    const f32x4 c = *(const f32x4*)(in_x + (size_t)(ib + gsel[2]) * 256 + lane * 4);
    ushort4 o4;
    o4.x = f2bf(w0 * a.x + w1 * b.x + w2 * c.x);
    o4.y = f2bf(w0 * a.y + w1 * b.y + w2 * c.y);
    o4.z = f2bf(w0 * a.z + w1 * b.z + w2 * c.z);
    o4.w = f2bf(w0 * a.w + w1 * b.w + w2 * c.w);
    *(ushort4*)&Hs[lr * HSTR + lane * 4] = o4;

    const float2 sv = *(const float2*)(skip_x + (size_t)s * 128 + lane * 2);
    ushort2 o2; o2.x = f2bf(sv.x); o2.y = f2bf(sv.y);
    *(ushort2*)&Hs[lr * HSTR + 256 + lane * 2] = o2;

    if (lane < 40) {   // pos(3) + zero-pad cols 387..423
      const float v = (lane == 0) ? sx : (lane == 1) ? sy : (lane == 2) ? sz : 0.f;
      Hs[lr * HSTR + 384 + lane] = f2bf(v);
    }
  }
  WAITL(); BAR();   // H-tile ready for all waves

  // frag byte/short offsets (swizzled B read; padded A reads)
  int woff[4], h1off[4], h2off[4];
#pragma unroll
  for (int i = 0; i < 4; ++i) {
    const int R = wc + i * 16 + fr;                  // W-row = output col
    woff[i]  = R * 32 + ((g ^ ((R >> 1) & 3)) << 3);
    h1off[i] = (i * 16 + fr) * HSTR + g * 8;
    h2off[i] = (i * 16 + fr) * H1STR + g * 8;
  }

  f32x4 acc[4][4] = {};   // [mc=col-band frag][rr=row frag]

  // ---- GEMM1: h1 = relu(H @ W1 + b1), swapped-operand MFMA ----
#pragma unroll 1
  for (int ks = 0; ks < NK1; ++ks) {
    if (ks < NK1 - 1) { WAITV(4); } else { WAITV(0); }
    BAR();
    const unsigned short* bb = Bst + (ks & 1) * 8192;
    bf16x8 wf[4], hf[4];
#pragma unroll
    for (int i = 0; i < 4; ++i) wf[i] = *(const bf16x8*)&bb[woff[i]];
#pragma unroll
    for (int i = 0; i < 4; ++i) hf[i] = *(const bf16x8*)&Hs[h1off[i] + ks * 32];
#pragma unroll
    for (int mc = 0; mc < 4; ++mc)
#pragma unroll
      for (int rr = 0; rr < 4; ++rr)
        acc[mc][rr] = __builtin_amdgcn_mfma_f32_16x16x32_bf16(
            wf[mc], hf[rr], acc[mc][rr], 0, 0, 0);
    WAITL(); BAR();
    if (ks + 2 < NK1) stage_tile(W1t, KPAD, ks + 2, Bst + (ks & 1) * 8192, tid, wid);
  }

  // GEMM2 prologue staging — hides under h1 epilogue
  stage_tile(W2t, 256, 0, Bst, tid, wid);
  stage_tile(W2t, 256, 1, Bst + 8192, tid, wid);

  // h1 epilogue: lane owns rows rr*16+fr, 4 consecutive cols -> ushort4
  unsigned short* h1s = Hs;   // alias dead H-tile
#pragma unroll
  for (int rr = 0; rr < 4; ++rr)
#pragma unroll
    for (int mc = 0; mc < 4; ++mc) {
      ushort4 o;
      o.x = f2bf(fmaxf(acc[mc][rr][0] + b1v[mc][0], 0.f));
      o.y = f2bf(fmaxf(acc[mc][rr][1] + b1v[mc][1], 0.f));
      o.z = f2bf(fmaxf(acc[mc][rr][2] + b1v[mc][2], 0.f));
      o.w = f2bf(fmaxf(acc[mc][rr][3] + b1v[mc][3], 0.f));
      *(ushort4*)&h1s[(rr * 16 + fr) * H1STR + wc + mc * 16 + g * 4] = o;
    }
  WAITL(); BAR();   // h1-tile visible

#pragma unroll
  for (int mc = 0; mc < 4; ++mc)
#pragma unroll
    for (int rr = 0; rr < 4; ++rr) acc[mc][rr] = f32x4{0.f, 0.f, 0.f, 0.f};

  // ---- GEMM2: out = relu(h1 @ W2 + b2) ----
#pragma unroll 1
  for (int ks = 0; ks < NK2; ++ks) {
    if (ks < NK2 - 1) { WAITV(4); } else { WAITV(0); }
    BAR();
    const unsigned short* bb = Bst + (ks & 1) * 8192;
    bf16x8 wf[4], hf[4];
#pragma unroll
    for (int i = 0; i < 4; ++i) wf[i] = *(const bf16x8*)&bb[woff[i]];
#pragma unroll
    for (int i = 0; i < 4; ++i) hf[i] = *(const bf16x8*)&h1s[h2off[i] + ks * 32];
#pragma unroll
    for (int mc = 0; mc < 4; ++mc)
#pragma unroll
      for (int rr = 0; rr < 4; ++rr)
        acc[mc][rr] = __builtin_amdgcn_mfma_f32_16x16x32_bf16(
            wf[mc], hf[rr], acc[mc][rr], 0, 0, 0);
    WAITL(); BAR();
    if (ks + 2 < NK2) stage_tile(W2t, 256, ks + 2, Bst + (ks & 1) * 8192, tid, wid);
  }

  // final epilogue: coalesced float4 stores
#pragma unroll
  for (int rr = 0; rr < 4; ++rr)
#pragma unroll
    for (int mc = 0; mc < 4; ++mc) {
      f32x4 o;
#pragma unroll
      for (int j = 0; j < 4; ++j) o[j] = fmaxf(acc[mc][rr][j] + b2v[mc][j], 0.f);
      *(f32x4*)(out + (size_t)(m0 + rr * 16 + fr) * 256 + wc + mc * 16 + g * 4) = o;
    }
}

// ---------------------------------------------------------------------------
extern "C" void kernel_launch(void* const* d_in, const int* in_sizes, int n_in,
                              void* d_out, int out_size, void* d_ws, size_t ws_size,
                              hipStream_t stream) {
  const float* in_x     = (const float*)d_in[0];
  const float* in_pos   = (const float*)d_in[1];
  const float* skip_x   = (const float*)d_in[3];
  const float* skip_pos = (const float*)d_in[4];
  const float* W1       = (const float*)d_in[6];
  const float* bias1    = (const float*)d_in[7];
  const float* W2       = (const float*)d_in[8];
  const float* bias2    = (const float*)d_in[9];

  char* ws = (char*)d_ws;
  unsigned short* W1t = (unsigned short*)(ws);             // 256*416*2 = 212,992
  unsigned short* W2t = (unsigned short*)(ws + 212992);    // 256*256*2 = 131,072

  prep_w<<<dim3(44), dim3(256), 0, stream>>>(W1, W2, W1t, W2t);
  fp_fused<<<dim3(MROWS / 64), dim3(256), 0, stream>>>(
      in_x, in_pos, skip_x, skip_pos, W1t, W2t, bias1, bias2, (float*)d_out);
}

// Round 3
// 47.479 us; speedup vs baseline: 1.4230x; 1.4230x over previous
//
#include <hip/hip_runtime.h>
#include <hip/hip_bf16.h>

// ---------------------------------------------------------------------------
// PointNet2 FP module, split pipeline:
//   prep_w:  W1->W1t[256][416] bf16, W2->W2t[256][256] bf16 (zero-pad K)
//   knn_h:   knn(k=3) + interpolate + concat -> H[16384][416] bf16
//   gemm_p3: h1 = relu(H @ W1 + b1)   (bf16 out)
//   gemm_p3: out = relu(h1 @ W2 + b2) (f32 out)
// GEMM: 128x128 tile, 4 waves, swapped-operand MFMA, 3-deep global_load_lds
// pipeline with counted vmcnt, XOR-swizzled staging (both-sides).
// ---------------------------------------------------------------------------

typedef __bf16 bf16x8 __attribute__((ext_vector_type(8)));
typedef float  f32x4  __attribute__((ext_vector_type(4)));

__device__ __forceinline__ unsigned short f2bf(float f) {
  __hip_bfloat16 h = __float2bfloat16(f);
  return __builtin_bit_cast(unsigned short, h);
}

#define GLDS16(G, L)                                                          \
  __builtin_amdgcn_global_load_lds(                                           \
      (const __attribute__((address_space(1))) void*)(G),                     \
      (__attribute__((address_space(3))) void*)(L), 16, 0, 0)

#define BAR()    __builtin_amdgcn_s_barrier()
#define WAITV(N) asm volatile("s_waitcnt vmcnt(" #N ")" ::: "memory")
#define WAITL()  asm volatile("s_waitcnt lgkmcnt(0)" ::: "memory")

static constexpr int MROWS = 16384;
static constexpr int KPAD  = 416;   // 13 * 32
static constexpr int KREAL = 387;

// ---------------- prep: W1t[256][416], W2t[256][256] bf16 (LDS transpose) ---
__global__ __launch_bounds__(256) void prep_w(
    const float* __restrict__ W1, const float* __restrict__ W2,
    unsigned short* __restrict__ W1t, unsigned short* __restrict__ W2t)
{
  __shared__ float T[64][65];
  int b = blockIdx.x;
  const float* S; unsigned short* D; int KP, Kreal, kb, nb;
  if (b < 28) { S = W1; D = W1t; KP = KPAD; Kreal = KREAL; kb = b >> 2; nb = b & 3; }
  else { b -= 28; S = W2; D = W2t; KP = 256; Kreal = 256; kb = b >> 2; nb = b & 3; }
  const int k0 = kb << 6, n0 = nb << 6;
  const int tr = threadIdx.x >> 4, tc = threadIdx.x & 15;
#pragma unroll
  for (int i = 0; i < 4; ++i) {
    const int k = k0 + i * 16 + tr;
    float4 v = make_float4(0.f, 0.f, 0.f, 0.f);
    if (k < Kreal) v = *(const float4*)(S + (size_t)k * 256 + n0 + tc * 4);
    T[i * 16 + tr][tc * 4 + 0] = v.x;
    T[i * 16 + tr][tc * 4 + 1] = v.y;
    T[i * 16 + tr][tc * 4 + 2] = v.z;
    T[i * 16 + tr][tc * 4 + 3] = v.w;
  }
  __syncthreads();
#pragma unroll
  for (int i = 0; i < 4; ++i) {
    const int n = n0 + i * 16 + tr;
    const int k = k0 + tc * 4;
    if (k < KP) {
      ushort4 o;
      o.x = f2bf(T[tc * 4 + 0][i * 16 + tr]);
      o.y = f2bf(T[tc * 4 + 1][i * 16 + tr]);
      o.z = f2bf(T[tc * 4 + 2][i * 16 + tr]);
      o.w = f2bf(T[tc * 4 + 3][i * 16 + tr]);
      *(ushort4*)(D + (size_t)n * KP + k) = o;
    }
  }
}

// ---------------- knn(k=3) + interpolate + concat -> H bf16 ----------------
// one wave per skip point; 4 skip points / block (all in one batch)
__global__ __launch_bounds__(256) void knn_h(
    const float* __restrict__ in_x,      // [4096, 256]
    const float* __restrict__ in_pos,    // [4096, 3]
    const float* __restrict__ skip_x,    // [16384, 128]
    const float* __restrict__ skip_pos,  // [16384, 3]
    unsigned short* __restrict__ H)      // [16384, 416] bf16
{
  __shared__ float P[3][256];            // batch in_pos, SoA
  const int tid = threadIdx.x;
  const int s0  = blockIdx.x << 2;       // first skip point of block
  const int ib  = (s0 >> 10) << 8;       // first in-point of batch
  {
    const float* bp = in_pos + (size_t)ib * 3;
    for (int i = tid; i < 768; i += 256) P[i % 3][i / 3] = bp[i];
  }
  __syncthreads();

  const int wid = tid >> 6, lane = tid & 63;
  const int s = s0 + wid;
  const float sx = skip_pos[(size_t)s * 3 + 0];
  const float sy = skip_pos[(size_t)s * 3 + 1];
  const float sz = skip_pos[(size_t)s * 3 + 2];

  // d2 in numpy op-order (no fma contraction) so selection matches reference
  float d2[4];
#pragma unroll
  for (int q = 0; q < 4; ++q) {
    const int i = lane + (q << 6);
    const float dx = __fsub_rn(sx, P[0][i]);
    const float dy = __fsub_rn(sy, P[1][i]);
    const float dz = __fsub_rn(sz, P[2][i]);
    d2[q] = __fadd_rn(__fadd_rn(__fmul_rn(dx, dx), __fmul_rn(dy, dy)),
                      __fmul_rn(dz, dz));
  }

  int   gsel[3];
  float wsel[3];
  float wsum = 0.f;
#pragma unroll
  for (int p = 0; p < 3; ++p) {
    float bd = d2[0];
    int   bi = lane;
#pragma unroll
    for (int q = 1; q < 4; ++q) {
      const int i = lane + (q << 6);
      if (d2[q] < bd) { bd = d2[q]; bi = i; }
    }
#pragma unroll
    for (int m = 1; m < 64; m <<= 1) {   // full-wave argmin butterfly
      const float od = __shfl_xor(bd, m);
      const int   oi = __shfl_xor(bi, m);
      if (od < bd || (od == bd && oi < bi)) { bd = od; bi = oi; }
    }
    const bool win = ((bi & 63) == lane);
    const int  qw  = bi >> 6;             // static-index removal (rule 20)
    d2[0] = (win && qw == 0) ? 3.4e38f : d2[0];
    d2[1] = (win && qw == 1) ? 3.4e38f : d2[1];
    d2[2] = (win && qw == 2) ? 3.4e38f : d2[2];
    d2[3] = (win && qw == 3) ? 3.4e38f : d2[3];
    gsel[p] = bi;
    // dist == sqrt(selected d2) (squares kill the sub-order sign flip)
    const float w = 1.0f / fmaxf(sqrtf(bd), 1e-10f);
    wsel[p] = w;
    wsum += w;
  }
  const float denom = wsum + 1e-16f;
  const float w0 = wsel[0] / denom;
  const float w1 = wsel[1] / denom;
  const float w2 = wsel[2] / denom;

  // interpolate 256 channels: 4 per lane, float4 loads
  const f32x4 a = *(const f32x4*)(in_x + (size_t)(ib + gsel[0]) * 256 + lane * 4);
  const f32x4 b = *(const f32x4*)(in_x + (size_t)(ib + gsel[1]) * 256 + lane * 4);
  const f32x4 c = *(const f32x4*)(in_x + (size_t)(ib + gsel[2]) * 256 + lane * 4);

  unsigned short* hr = H + (size_t)s * KPAD;
  ushort4 o4;
  o4.x = f2bf(w0 * a.x + w1 * b.x + w2 * c.x);
  o4.y = f2bf(w0 * a.y + w1 * b.y + w2 * c.y);
  o4.z = f2bf(w0 * a.z + w1 * b.z + w2 * c.z);
  o4.w = f2bf(w0 * a.w + w1 * b.w + w2 * c.w);
  *(ushort4*)(hr + (lane << 2)) = o4;

  const float2 sv = ((const float2*)(skip_x + (size_t)s * 128))[lane];
  ushort2 o2;
  o2.x = f2bf(sv.x);
  o2.y = f2bf(sv.y);
  *(ushort2*)(hr + 256 + (lane << 1)) = o2;

  if (lane < 32) {   // pos(3) + zero-pad cols 387..415
    float v = (lane == 0) ? sx : (lane == 1) ? sy : (lane == 2) ? sz : 0.f;
    hr[384 + lane] = f2bf(v);
  }
}

// ---------------- GEMM: Out = relu(A[M,K] @ Bt[256,K]^T + bias) ------------
// 128x128 tile, 4 waves (each 64x64), swapped-operand MFMA, 3-deep pipeline.
template <int K, int NK, bool OUT_BF16>
__global__ __launch_bounds__(256) void gemm_p3(
    const unsigned short* __restrict__ A,   // [M, K] bf16
    const unsigned short* __restrict__ Bt,  // [256, K] bf16 (= W transposed)
    const float* __restrict__ bias,         // [256]
    void* __restrict__ Out)                 // [M, 256] bf16 or f32
{
  __shared__ unsigned short As[4][128 * 32];   // 4 pipeline buffers
  __shared__ unsigned short Bs[4][128 * 32];   // total 64 KiB
  const int tid = threadIdx.x, lane = tid & 63, wid = tid >> 6;
  const int m0 = blockIdx.x << 7, n0 = blockIdx.y << 7;
  const int fr = lane & 15, g = lane >> 4;
  const int wr = (wid >> 1) << 6, wcc = (wid & 1) << 6;

  // stage source: thread t -> row t/4, chunk (t%4) XOR-swizzled by row
  const int r  = tid >> 2;
  const int cs = (tid & 3) ^ ((r >> 1) & 3);   // ((r+64)>>1)&3 == (r>>1)&3
  const unsigned short* gA0 = A + (size_t)(m0 + r) * K + cs * 8;
  const unsigned short* gA1 = gA0 + (size_t)64 * K;
  const unsigned short* gB0 = Bt + (size_t)(n0 + r) * K + cs * 8;
  const unsigned short* gB1 = gB0 + (size_t)64 * K;

#define STAGE(ks, b)                                                          \
  {                                                                           \
    const int _ko = (ks) * 32;                                                \
    GLDS16(gA0 + _ko, &As[b][wid * 512]);                                     \
    GLDS16(gA1 + _ko, &As[b][2048 + wid * 512]);                              \
    GLDS16(gB0 + _ko, &Bs[b][wid * 512]);                                     \
    GLDS16(gB1 + _ko, &Bs[b][2048 + wid * 512]);                              \
  }

  // fragment read offsets (XOR on read side matches pre-swizzled source)
  int woff[4], hoff[4];
#pragma unroll
  for (int i = 0; i < 4; ++i) {
    const int Rw = wcc + i * 16 + fr;
    const int Rh = wr + i * 16 + fr;
    woff[i] = Rw * 32 + ((g ^ ((Rw >> 1) & 3)) << 3);
    hoff[i] = Rh * 32 + ((g ^ ((Rh >> 1) & 3)) << 3);
  }

  STAGE(0, 0); STAGE(1, 1); STAGE(2, 2);

  f32x4 acc[4][4] = {};   // [mc = col frag][rr = row frag]

#pragma unroll 1
  for (int ks = 0; ks < NK; ++ks) {
    if (ks + 3 < NK) STAGE(ks + 3, (ks + 3) & 3);
    const int rem = NK - 1 - ks;
    if (rem >= 3)      { WAITV(12); }
    else if (rem == 2) { WAITV(8); }
    else if (rem == 1) { WAITV(4); }
    else               { WAITV(0); }
    BAR();
    const unsigned short* as = As[ks & 3];
    const unsigned short* bs = Bs[ks & 3];
    bf16x8 wf[4], hf[4];
#pragma unroll
    for (int i = 0; i < 4; ++i) wf[i] = *(const bf16x8*)&bs[woff[i]];
#pragma unroll
    for (int i = 0; i < 4; ++i) hf[i] = *(const bf16x8*)&as[hoff[i]];
#pragma unroll
    for (int mc = 0; mc < 4; ++mc)
#pragma unroll
      for (int rr = 0; rr < 4; ++rr)
        acc[mc][rr] = __builtin_amdgcn_mfma_f32_16x16x32_bf16(
            wf[mc], hf[rr], acc[mc][rr], 0, 0, 0);
    WAITL(); BAR();   // all waves done reading buf before it's restaged
  }
#undef STAGE

  // epilogue: lane owns row (wr+rr*16+fr), 4 consecutive cols per frag
  f32x4 bv[4];
#pragma unroll
  for (int mc = 0; mc < 4; ++mc)
    bv[mc] = *(const f32x4*)(bias + n0 + wcc + mc * 16 + g * 4);
#pragma unroll
  for (int rr = 0; rr < 4; ++rr) {
    const size_t row = (size_t)(m0 + wr + rr * 16 + fr);
#pragma unroll
    for (int mc = 0; mc < 4; ++mc) {
      const int col = n0 + wcc + mc * 16 + g * 4;
      if constexpr (OUT_BF16) {
        ushort4 o;
        o.x = f2bf(fmaxf(acc[mc][rr][0] + bv[mc][0], 0.f));
        o.y = f2bf(fmaxf(acc[mc][rr][1] + bv[mc][1], 0.f));
        o.z = f2bf(fmaxf(acc[mc][rr][2] + bv[mc][2], 0.f));
        o.w = f2bf(fmaxf(acc[mc][rr][3] + bv[mc][3], 0.f));
        *(ushort4*)((unsigned short*)Out + row * 256 + col) = o;
      } else {
        f32x4 o;
#pragma unroll
        for (int j = 0; j < 4; ++j) o[j] = fmaxf(acc[mc][rr][j] + bv[mc][j], 0.f);
        *(f32x4*)((float*)Out + row * 256 + col) = o;
      }
    }
  }
}

// ---------------------------------------------------------------------------
extern "C" void kernel_launch(void* const* d_in, const int* in_sizes, int n_in,
                              void* d_out, int out_size, void* d_ws, size_t ws_size,
                              hipStream_t stream) {
  const float* in_x     = (const float*)d_in[0];
  const float* in_pos   = (const float*)d_in[1];
  const float* skip_x   = (const float*)d_in[3];
  const float* skip_pos = (const float*)d_in[4];
  const float* W1       = (const float*)d_in[6];
  const float* bias1    = (const float*)d_in[7];
  const float* W2       = (const float*)d_in[8];
  const float* bias2    = (const float*)d_in[9];

  char* ws = (char*)d_ws;
  unsigned short* W1t = (unsigned short*)(ws);                       // 212,992 B
  unsigned short* W2t = (unsigned short*)(ws + 212992);              // 131,072 B
  unsigned short* H   = (unsigned short*)(ws + 212992 + 131072);     // 13,631,488 B
  unsigned short* h1  = (unsigned short*)(ws + 212992 + 131072 + 13631488);  // 8,388,608 B

  prep_w<<<dim3(44), dim3(256), 0, stream>>>(W1, W2, W1t, W2t);
  knn_h<<<dim3(MROWS / 4), dim3(256), 0, stream>>>(in_x, in_pos, skip_x,
                                                   skip_pos, H);
  gemm_p3<KPAD, 13, true><<<dim3(MROWS / 128, 2), dim3(256), 0, stream>>>(
      H, W1t, bias1, (void*)h1);
  gemm_p3<256, 8, false><<<dim3(MROWS / 128, 2), dim3(256), 0, stream>>>(
      h1, W2t, bias2, d_out);
}

// Round 4
// 40.276 us; speedup vs baseline: 1.6775x; 1.1788x over previous
//
#include <hip/hip_runtime.h>
#include <hip/hip_bf16.h>

// ---------------------------------------------------------------------------
// PointNet2 FP module, 2-launch pipeline:
//   knn_prep: blocks 0..43  -> W1t[256][416], W2t[256][256] bf16 (transposed)
//             blocks 44..   -> knn(k=3)+interp+concat -> H[16384][416] bf16
//   gemm12:   per 64-row strip: h1 = relu(H@W1+b1) in LDS, out = relu(h1@W2+b2)
//             (GEMM1 N=256 fits one block -> no grid sync, no h1 round-trip)
// GEMM: swapped-operand MFMA 16x16x32_bf16, 4-buffer 3-deep global_load_lds
// pipeline, counted vmcnt (never mid-loop drain), XOR-swizzle both-sides.
// ---------------------------------------------------------------------------

typedef __bf16 bf16x8 __attribute__((ext_vector_type(8)));
typedef float  f32x4  __attribute__((ext_vector_type(4)));

__device__ __forceinline__ unsigned short f2bf(float f) {
  __hip_bfloat16 h = __float2bfloat16(f);
  return __builtin_bit_cast(unsigned short, h);
}

#define GLDS16(G, L)                                                          \
  __builtin_amdgcn_global_load_lds(                                           \
      (const __attribute__((address_space(1))) void*)(G),                     \
      (__attribute__((address_space(3))) void*)(L), 16, 0, 0)

#define BAR()    __builtin_amdgcn_s_barrier()
#define WAITV(N) asm volatile("s_waitcnt vmcnt(" #N ")" ::: "memory")
#define WAITL()  asm volatile("s_waitcnt lgkmcnt(0)" ::: "memory")

static constexpr int MROWS = 16384;
static constexpr int KPAD  = 416;   // 13 * 32
static constexpr int KREAL = 387;
static constexpr int NK1   = 13;
static constexpr int NK2   = 8;
static constexpr int H1STR = 264;   // h1 LDS row stride (shorts)

// ------------------- kernel A: weight prep + knn/interp/concat -------------
__global__ __launch_bounds__(256) void knn_prep(
    const float* __restrict__ in_x,      // [4096, 256]
    const float* __restrict__ in_pos,    // [4096, 3]
    const float* __restrict__ skip_x,    // [16384, 128]
    const float* __restrict__ skip_pos,  // [16384, 3]
    const float* __restrict__ W1, const float* __restrict__ W2,
    unsigned short* __restrict__ W1t, unsigned short* __restrict__ W2t,
    unsigned short* __restrict__ H)      // [16384, 416] bf16
{
  __shared__ float T[64][65];
  __shared__ float P[3][256];
  const int tid = threadIdx.x;

  if (blockIdx.x < 44) {   // ---------------- weight transpose+cast ----------
    int b = blockIdx.x;
    const float* S; unsigned short* D; int KP, Kreal, kb, nb;
    if (b < 28) { S = W1; D = W1t; KP = KPAD; Kreal = KREAL; kb = b >> 2; nb = b & 3; }
    else { b -= 28; S = W2; D = W2t; KP = 256; Kreal = 256; kb = b >> 2; nb = b & 3; }
    const int k0 = kb << 6, n0 = nb << 6;
    const int tr = tid >> 4, tc = tid & 15;
#pragma unroll
    for (int i = 0; i < 4; ++i) {
      const int k = k0 + i * 16 + tr;
      float4 v = make_float4(0.f, 0.f, 0.f, 0.f);
      if (k < Kreal) v = *(const float4*)(S + (size_t)k * 256 + n0 + tc * 4);
      T[i * 16 + tr][tc * 4 + 0] = v.x;
      T[i * 16 + tr][tc * 4 + 1] = v.y;
      T[i * 16 + tr][tc * 4 + 2] = v.z;
      T[i * 16 + tr][tc * 4 + 3] = v.w;
    }
    __syncthreads();
#pragma unroll
    for (int i = 0; i < 4; ++i) {
      const int n = n0 + i * 16 + tr;
      const int k = k0 + tc * 4;
      if (k < KP) {
        ushort4 o;
        o.x = f2bf(T[tc * 4 + 0][i * 16 + tr]);
        o.y = f2bf(T[tc * 4 + 1][i * 16 + tr]);
        o.z = f2bf(T[tc * 4 + 2][i * 16 + tr]);
        o.w = f2bf(T[tc * 4 + 3][i * 16 + tr]);
        *(ushort4*)(D + (size_t)n * KP + k) = o;
      }
    }
    return;
  }

  // ---------------- knn(k=3) + interpolate + concat -> H ----------
  const int s0 = (blockIdx.x - 44) << 2;   // first skip point of block
  const int ib = (s0 >> 10) << 8;          // first in-point of batch
  {
    const float* bp = in_pos + (size_t)ib * 3;
    for (int i = tid; i < 768; i += 256) P[i % 3][i / 3] = bp[i];
  }
  __syncthreads();

  const int wid = tid >> 6, lane = tid & 63;
  const int s = s0 + wid;
  const float sx = skip_pos[(size_t)s * 3 + 0];
  const float sy = skip_pos[(size_t)s * 3 + 1];
  const float sz = skip_pos[(size_t)s * 3 + 2];

  float d2[4];
#pragma unroll
  for (int q = 0; q < 4; ++q) {   // numpy op-order, no fma contraction
    const int i = lane + (q << 6);
    const float dx = __fsub_rn(sx, P[0][i]);
    const float dy = __fsub_rn(sy, P[1][i]);
    const float dz = __fsub_rn(sz, P[2][i]);
    d2[q] = __fadd_rn(__fadd_rn(__fmul_rn(dx, dx), __fmul_rn(dy, dy)),
                      __fmul_rn(dz, dz));
  }

  int gsel[3]; float wsel[3]; float wsum = 0.f;
#pragma unroll
  for (int p = 0; p < 3; ++p) {
    float bd = d2[0]; int bi = lane;
#pragma unroll
    for (int q = 1; q < 4; ++q) {
      const int i = lane + (q << 6);
      if (d2[q] < bd) { bd = d2[q]; bi = i; }
    }
#pragma unroll
    for (int m = 1; m < 64; m <<= 1) {   // argmin butterfly, low-idx tiebreak
      const float od = __shfl_xor(bd, m);
      const int   oi = __shfl_xor(bi, m);
      if (od < bd || (od == bd && oi < bi)) { bd = od; bi = oi; }
    }
    const bool win = ((bi & 63) == lane);
    const int  qw  = bi >> 6;             // static-index removal (rule 20)
    d2[0] = (win && qw == 0) ? 3.4e38f : d2[0];
    d2[1] = (win && qw == 1) ? 3.4e38f : d2[1];
    d2[2] = (win && qw == 2) ? 3.4e38f : d2[2];
    d2[3] = (win && qw == 3) ? 3.4e38f : d2[3];
    gsel[p] = bi;
    const float w = 1.0f / fmaxf(sqrtf(bd), 1e-10f);
    wsel[p] = w; wsum += w;
  }
  const float denom = wsum + 1e-16f;
  const float w0 = wsel[0] / denom;
  const float w1 = wsel[1] / denom;
  const float w2 = wsel[2] / denom;

  const f32x4 a = *(const f32x4*)(in_x + (size_t)(ib + gsel[0]) * 256 + lane * 4);
  const f32x4 b = *(const f32x4*)(in_x + (size_t)(ib + gsel[1]) * 256 + lane * 4);
  const f32x4 c = *(const f32x4*)(in_x + (size_t)(ib + gsel[2]) * 256 + lane * 4);

  unsigned short* hr = H + (size_t)s * KPAD;
  ushort4 o4;
  o4.x = f2bf(w0 * a.x + w1 * b.x + w2 * c.x);
  o4.y = f2bf(w0 * a.y + w1 * b.y + w2 * c.y);
  o4.z = f2bf(w0 * a.z + w1 * b.z + w2 * c.z);
  o4.w = f2bf(w0 * a.w + w1 * b.w + w2 * c.w);
  *(ushort4*)(hr + (lane << 2)) = o4;

  const float2 sv = ((const float2*)(skip_x + (size_t)s * 128))[lane];
  ushort2 o2; o2.x = f2bf(sv.x); o2.y = f2bf(sv.y);
  *(ushort2*)(hr + 256 + (lane << 1)) = o2;

  if (lane < 32) {   // pos(3) + zero-pad cols 387..415
    float v = (lane == 0) ? sx : (lane == 1) ? sy : (lane == 2) ? sz : 0.f;
    hr[384 + lane] = f2bf(v);
  }
}

// ------------------- kernel B: fused GEMM1 -> LDS h1 -> GEMM2 --------------
// grid 256 blocks, 4 waves; block owns rows m0..m0+63, all 256 cols.
__global__ __launch_bounds__(256) void gemm12(
    const unsigned short* __restrict__ Hg,   // [16384, 416] bf16
    const unsigned short* __restrict__ W1t,  // [256][416]  bf16
    const unsigned short* __restrict__ W2t,  // [256][256]  bf16
    const float* __restrict__ bias1, const float* __restrict__ bias2,
    float* __restrict__ out)                 // [16384, 256]
{
  __shared__ unsigned short As[4][64 * 32];    // 16 KiB  (H K-chunks)
  __shared__ unsigned short Bs[4][256 * 32];   // 64 KiB  (W K-chunks)
  __shared__ unsigned short h1s[64 * H1STR];   // 33 KiB  (full h1 strip)

  const int tid = threadIdx.x, lane = tid & 63, wid = tid >> 6;
  const int m0 = blockIdx.x << 6;
  const int fr = lane & 15, g = lane >> 4;
  const int wcc = wid << 6;                    // wave's 64-col band

  // stage source addressing: thread t -> row t/4, chunk (t%4) XOR row-swizzle
  const int r  = tid >> 2;                     // 0..63
  const int cs = (tid & 3) ^ ((r >> 1) & 3);
  const unsigned short* gA   = Hg  + (size_t)(m0 + r) * KPAD + cs * 8;
  const unsigned short* gB10 = W1t + (size_t)r * KPAD + cs * 8;
  const unsigned short* gB20 = W2t + (size_t)r * 256  + cs * 8;

#define STAGE1(ks, bu)                                                        \
  {                                                                           \
    const int _ko = (ks) * 32;                                                \
    GLDS16(gA + _ko, &As[bu][wid * 512]);                                     \
    GLDS16(gB10 + _ko,                 &Bs[bu][wid * 512]);                   \
    GLDS16(gB10 + 64 * KPAD + _ko,     &Bs[bu][2048 + wid * 512]);            \
    GLDS16(gB10 + 128 * KPAD + _ko,    &Bs[bu][4096 + wid * 512]);            \
    GLDS16(gB10 + 192 * KPAD + _ko,    &Bs[bu][6144 + wid * 512]);            \
  }
#define STAGE2(ks, bu)                                                        \
  {                                                                           \
    const int _ko = (ks) * 32;                                                \
    GLDS16(gB20 + _ko,                 &Bs[bu][wid * 512]);                   \
    GLDS16(gB20 + 64 * 256 + _ko,      &Bs[bu][2048 + wid * 512]);            \
    GLDS16(gB20 + 128 * 256 + _ko,     &Bs[bu][4096 + wid * 512]);            \
    GLDS16(gB20 + 192 * 256 + _ko,     &Bs[bu][6144 + wid * 512]);            \
  }

  STAGE1(0, 0); STAGE1(1, 1); STAGE1(2, 2);   // prologue: 15 loads in flight

  // fragment read offsets (XOR read side matches pre-swizzled source)
  int woff[4], hoff[4], h2off[4];
#pragma unroll
  for (int i = 0; i < 4; ++i) {
    const int Rw = wcc + i * 16 + fr;          // W row (0..255) = output col
    const int Rh = i * 16 + fr;                // H row (0..63)  = output row
    woff[i]  = Rw * 32 + ((g ^ ((Rw >> 1) & 3)) << 3);
    hoff[i]  = Rh * 32 + ((g ^ ((Rh >> 1) & 3)) << 3);
    h2off[i] = Rh * H1STR + g * 8;             // padded stride, no swizzle
  }

  f32x4 bv1[4], bv2[4];
#pragma unroll
  for (int mc = 0; mc < 4; ++mc) {
    bv1[mc] = *(const f32x4*)(bias1 + wcc + mc * 16 + g * 4);
    bv2[mc] = *(const f32x4*)(bias2 + wcc + mc * 16 + g * 4);
  }

  f32x4 acc[4][4] = {};   // [mc = col frag][rr = row frag]

  // ---- GEMM1: 13 K-steps, 4-buffer 3-deep pipeline (5 loads/stage) ----
#pragma unroll 1
  for (int ks = 0; ks < NK1; ++ks) {
    if (ks + 3 < NK1) STAGE1(ks + 3, (ks + 3) & 3);
    const int rem = NK1 - 1 - ks;
    if (rem >= 3)      { WAITV(15); }
    else if (rem == 2) { WAITV(10); }
    else if (rem == 1) { WAITV(5); }
    else               { WAITV(0); }
    BAR();
    const unsigned short* as = As[ks & 3];
    const unsigned short* bs = Bs[ks & 3];
    bf16x8 wf[4], hf[4];
#pragma unroll
    for (int i = 0; i < 4; ++i) wf[i] = *(const bf16x8*)&bs[woff[i]];
#pragma unroll
    for (int i = 0; i < 4; ++i) hf[i] = *(const bf16x8*)&as[hoff[i]];
#pragma unroll
    for (int mc = 0; mc < 4; ++mc)
#pragma unroll
      for (int rr = 0; rr < 4; ++rr)
        acc[mc][rr] = __builtin_amdgcn_mfma_f32_16x16x32_bf16(
            wf[mc], hf[rr], acc[mc][rr], 0, 0, 0);
    WAITL(); BAR();   // all waves done with buf before restage
  }

  // GEMM2 prologue staging — latency hides under h1 epilogue
  STAGE2(0, 0); STAGE2(1, 1); STAGE2(2, 2);

  // h1 epilogue: bias+relu+bf16 -> LDS strip (lane owns rows rr*16+fr)
#pragma unroll
  for (int rr = 0; rr < 4; ++rr)
#pragma unroll
    for (int mc = 0; mc < 4; ++mc) {
      ushort4 o;
      o.x = f2bf(fmaxf(acc[mc][rr][0] + bv1[mc][0], 0.f));
      o.y = f2bf(fmaxf(acc[mc][rr][1] + bv1[mc][1], 0.f));
      o.z = f2bf(fmaxf(acc[mc][rr][2] + bv1[mc][2], 0.f));
      o.w = f2bf(fmaxf(acc[mc][rr][3] + bv1[mc][3], 0.f));
      *(ushort4*)&h1s[(rr * 16 + fr) * H1STR + wcc + mc * 16 + g * 4] = o;
    }
  WAITL(); BAR();   // h1 strip visible to all waves

#pragma unroll
  for (int mc = 0; mc < 4; ++mc)
#pragma unroll
    for (int rr = 0; rr < 4; ++rr) acc[mc][rr] = f32x4{0.f, 0.f, 0.f, 0.f};

  // ---- GEMM2: 8 K-steps, A from LDS h1s, B pipelined (4 loads/stage) ----
#pragma unroll 1
  for (int ks = 0; ks < NK2; ++ks) {
    if (ks + 3 < NK2) STAGE2(ks + 3, (ks + 3) & 3);
    const int rem = NK2 - 1 - ks;
    if (rem >= 3)      { WAITV(12); }
    else if (rem == 2) { WAITV(8); }
    else if (rem == 1) { WAITV(4); }
    else               { WAITV(0); }
    BAR();
    const unsigned short* bs = Bs[ks & 3];
    bf16x8 wf[4], hf[4];
#pragma unroll
    for (int i = 0; i < 4; ++i) wf[i] = *(const bf16x8*)&bs[woff[i]];
#pragma unroll
    for (int i = 0; i < 4; ++i) hf[i] = *(const bf16x8*)&h1s[h2off[i] + ks * 32];
#pragma unroll
    for (int mc = 0; mc < 4; ++mc)
#pragma unroll
      for (int rr = 0; rr < 4; ++rr)
        acc[mc][rr] = __builtin_amdgcn_mfma_f32_16x16x32_bf16(
            wf[mc], hf[rr], acc[mc][rr], 0, 0, 0);
    WAITL(); BAR();
  }
#undef STAGE1
#undef STAGE2

  // final epilogue: coalesced float4 stores
#pragma unroll
  for (int rr = 0; rr < 4; ++rr) {
    const size_t row = (size_t)(m0 + rr * 16 + fr);
#pragma unroll
    for (int mc = 0; mc < 4; ++mc) {
      f32x4 o;
#pragma unroll
      for (int j = 0; j < 4; ++j) o[j] = fmaxf(acc[mc][rr][j] + bv2[mc][j], 0.f);
      *(f32x4*)(out + row * 256 + wcc + mc * 16 + g * 4) = o;
    }
  }
}

// ---------------------------------------------------------------------------
extern "C" void kernel_launch(void* const* d_in, const int* in_sizes, int n_in,
                              void* d_out, int out_size, void* d_ws, size_t ws_size,
                              hipStream_t stream) {
  const float* in_x     = (const float*)d_in[0];
  const float* in_pos   = (const float*)d_in[1];
  const float* skip_x   = (const float*)d_in[3];
  const float* skip_pos = (const float*)d_in[4];
  const float* W1       = (const float*)d_in[6];
  const float* bias1    = (const float*)d_in[7];
  const float* W2       = (const float*)d_in[8];
  const float* bias2    = (const float*)d_in[9];

  char* ws = (char*)d_ws;
  unsigned short* W1t = (unsigned short*)(ws);                    // 212,992 B
  unsigned short* W2t = (unsigned short*)(ws + 212992);           // 131,072 B
  unsigned short* H   = (unsigned short*)(ws + 212992 + 131072);  // 13,631,488 B

  knn_prep<<<dim3(44 + MROWS / 4), dim3(256), 0, stream>>>(
      in_x, in_pos, skip_x, skip_pos, W1, W2, W1t, W2t, H);
  gemm12<<<dim3(MROWS / 64), dim3(256), 0, stream>>>(
      H, W1t, W2t, bias1, bias2, (float*)d_out);
}